// Round 7
// baseline (168.278 us; speedup 1.0000x reference)
//
#include <hip/hip_runtime.h>

#define SS 30
#define QQ 16
#define NV1 21
#define NV2 11
#define NVT 32
#define NB 8                   // batches per block
#define ROWS (NB * SS)         // 240
#define CT (NB * (SS / 2))     // 120 compute threads (2 rows each)
#define THREADS 128

#define LOG2E 1.44269504088896340736f

typedef float v2f __attribute__((ext_vector_type(2)));
typedef float v4f __attribute__((ext_vector_type(4)));

__device__ __forceinline__ v2f bcast(float x) { v2f r; r.x = x; r.y = x; return r; }
__device__ __forceinline__ v2f pkfma(v2f a, v2f b, v2f c) {
    return __builtin_elementwise_fma(a, b, c);   // -> v_pk_fma_f32 on gfx950
}

__global__ __launch_bounds__(THREADS, 6) void fused_dual_attn(
    const float* __restrict__ x,
    const float* __restrict__ q1w, const float* __restrict__ q1b,
    const float* __restrict__ k1w, const float* __restrict__ k1b,
    const float* __restrict__ v1w, const float* __restrict__ v1b,
    const float* __restrict__ q2w, const float* __restrict__ q2b,
    const float* __restrict__ k2w, const float* __restrict__ k2b,
    const float* __restrict__ v2w, const float* __restrict__ v2b,
    float* __restrict__ out1, float* __restrict__ out2)
{
    __shared__ v4f xsv[ROWS];        // 3.84 KB staged x
    __shared__ float cm[2][20];      // per branch: log2e*(M[16], w[4])
    __shared__ v4f  vwt[NVT];        // V weights * 2*log2e
    __shared__ float vbl[NVT];       // V bias * 2*log2e
    __shared__ v4f  h1s[ROWS];       // normalized context, branch 1
    __shared__ v4f  h2s[ROWS];       // branch 2

    const int tid = threadIdx.x;
    const long long blk = blockIdx.x;

    // ---- per-block weight-derived constants (scaled by log2e) ----
    if (tid < 40) {
        const int br = tid / 20, idx = tid % 20;
        const float* qw = br ? q2w : q1w;
        const float* qb = br ? q2b : q1b;
        const float* kw = br ? k2w : k1w;
        float acc = 0.f;
        if (idx < 16) {
            const int d = idx >> 2, e = idx & 3;
            #pragma unroll
            for (int q = 0; q < QQ; ++q) acc += qw[d * QQ + q] * kw[e * QQ + q];
        } else {
            const int e = idx - 16;
            #pragma unroll
            for (int q = 0; q < QQ; ++q) acc += kw[e * QQ + q] * qb[q];
        }
        cm[br][idx] = acc * LOG2E;
    }
    if (tid >= 64 && tid < 64 + NVT) {
        const int o = tid - 64;
        const float s2l = 2.0f * LOG2E;
        v4f w;
        if (o < NV1) {
            w.x = v1w[o] * s2l; w.y = v1w[NV1 + o] * s2l;
            w.z = v1w[2 * NV1 + o] * s2l; w.w = v1w[3 * NV1 + o] * s2l;
            vbl[o] = v1b[o] * s2l;
        } else {
            const int p = o - NV1;
            w.x = v2w[p] * s2l; w.y = v2w[NV2 + p] * s2l;
            w.z = v2w[2 * NV2 + p] * s2l; w.w = v2w[3 * NV2 + p] * s2l;
            vbl[o] = v2b[p] * s2l;
        }
        vwt[o] = w;
    }

    // ---- stage x (coalesced, nontemporal) ----
    {
        const v4f* xg = reinterpret_cast<const v4f*>(x) + blk * ROWS;
        for (int i = tid; i < ROWS; i += THREADS)
            xsv[i] = __builtin_nontemporal_load(xg + i);
    }
    __syncthreads();

    // ---- compute: 2 rows per thread (row-packed lo/hi), builtin packed FMA ----
    if (tid < CT) {
        const int batch = (unsigned)tid / 15;
        const int sA = tid - batch * 15;
        const int rowA = batch * SS + sA;
        const int rowB = rowA + 15;
        const v4f* xb = xsv + batch * SS;
        const v4f xA = xsv[rowA];
        const v4f xB = xsv[rowB];

        v2f g1p[4], g2p[4];
        #pragma unroll
        for (int e = 0; e < 4; ++e) {
            g1p[e].x = cm[0][16 + e] + xA.x * cm[0][e] + xA.y * cm[0][4 + e]
                     + xA.z * cm[0][8 + e] + xA.w * cm[0][12 + e];
            g1p[e].y = cm[0][16 + e] + xB.x * cm[0][e] + xB.y * cm[0][4 + e]
                     + xB.z * cm[0][8 + e] + xB.w * cm[0][12 + e];
            g2p[e].x = cm[1][16 + e] + xA.x * cm[1][e] + xA.y * cm[1][4 + e]
                     + xA.z * cm[1][8 + e] + xA.w * cm[1][12 + e];
            g2p[e].y = cm[1][16 + e] + xB.x * cm[1][e] + xB.y * cm[1][4 + e]
                     + xB.z * cm[1][8 + e] + xB.w * cm[1][12 + e];
        }

        v2f sum1 = {0.f, 0.f}, sum2 = {0.f, 0.f};
        v2f h1p[4], h2p[4];
        #pragma unroll
        for (int e = 0; e < 4; ++e) { h1p[e] = sum1; h2p[e] = sum1; }

        #pragma unroll
        for (int t = 0; t < SS; ++t) {
            const v4f xt = xb[t];
            const v2f bx = bcast(xt.x), by = bcast(xt.y), bz = bcast(xt.z), bw = bcast(xt.w);
            v2f s1 = g1p[3] * bw;
            s1 = pkfma(g1p[2], bz, s1);
            s1 = pkfma(g1p[1], by, s1);
            s1 = pkfma(g1p[0], bx, s1);
            v2f s2 = g2p[3] * bw;
            s2 = pkfma(g2p[2], bz, s2);
            s2 = pkfma(g2p[1], by, s2);
            s2 = pkfma(g2p[0], bx, s2);
            v2f p1, p2;
            p1.x = __builtin_amdgcn_exp2f(s1.x);
            p1.y = __builtin_amdgcn_exp2f(s1.y);
            p2.x = __builtin_amdgcn_exp2f(s2.x);
            p2.y = __builtin_amdgcn_exp2f(s2.y);
            sum1 = sum1 + p1;
            sum2 = sum2 + p2;
            h1p[0] = pkfma(p1, bx, h1p[0]);
            h1p[1] = pkfma(p1, by, h1p[1]);
            h1p[2] = pkfma(p1, bz, h1p[2]);
            h1p[3] = pkfma(p1, bw, h1p[3]);
            h2p[0] = pkfma(p2, bx, h2p[0]);
            h2p[1] = pkfma(p2, by, h2p[1]);
            h2p[2] = pkfma(p2, bz, h2p[2]);
            h2p[3] = pkfma(p2, bw, h2p[3]);
        }
        const float i1A = __builtin_amdgcn_rcpf(sum1.x);
        const float i1B = __builtin_amdgcn_rcpf(sum1.y);
        const float i2A = __builtin_amdgcn_rcpf(sum2.x);
        const float i2B = __builtin_amdgcn_rcpf(sum2.y);
        v4f hA1; hA1.x = h1p[0].x * i1A; hA1.y = h1p[1].x * i1A; hA1.z = h1p[2].x * i1A; hA1.w = h1p[3].x * i1A;
        v4f hB1; hB1.x = h1p[0].y * i1B; hB1.y = h1p[1].y * i1B; hB1.z = h1p[2].y * i1B; hB1.w = h1p[3].y * i1B;
        v4f hA2; hA2.x = h2p[0].x * i2A; hA2.y = h2p[1].x * i2A; hA2.z = h2p[2].x * i2A; hA2.w = h2p[3].x * i2A;
        v4f hB2; hB2.x = h2p[0].y * i2B; hB2.y = h2p[1].y * i2B; hB2.z = h2p[2].y * i2B; hB2.w = h2p[3].y * i2B;
        h1s[rowA] = hA1; h1s[rowB] = hB1;
        h2s[rowA] = hA2; h2s[rowB] = hB2;
    }
    __syncthreads();

    // ---- write phase: V-projection + tanh fused into nontemporal stores ----
    {
        const int n1 = ROWS * NV1 / 4;   // 1260
        v4f* dst1 = reinterpret_cast<v4f*>(out1) + blk * n1;
        for (int i = tid; i < n1; i += THREADS) {
            const int e0 = i * 4;
            v4f val;
            #pragma unroll
            for (int j = 0; j < 4; ++j) {
                const unsigned e = e0 + j;
                const unsigned r = e / NV1;
                const unsigned o = e - r * NV1;
                const v4f h = h1s[r];
                const v4f w = vwt[o];
                const float v = vbl[o] + fmaf(h.x, w.x, fmaf(h.y, w.y, fmaf(h.z, w.z, h.w * w.w)));
                const float ex = __builtin_amdgcn_exp2f(v);       // exp(2*orig) via folded scale
                const float rr = __builtin_amdgcn_rcpf(ex + 1.0f);
                val[j] = fmaf(-2.0f, rr, 1.0f);                   // tanh
            }
            __builtin_nontemporal_store(val, dst1 + i);
        }

        const int n2 = ROWS * NV2 / 4;   // 660
        v4f* dst2 = reinterpret_cast<v4f*>(out2) + blk * n2;
        for (int i = tid; i < n2; i += THREADS) {
            const int e0 = i * 4;
            v4f val;
            #pragma unroll
            for (int j = 0; j < 4; ++j) {
                const unsigned e = e0 + j;
                const unsigned r = e / NV2;
                const unsigned o = e - r * NV2;
                const v4f h = h2s[r];
                const v4f w = vwt[NV1 + o];
                const float v = vbl[NV1 + o] + fmaf(h.x, w.x, fmaf(h.y, w.y, fmaf(h.z, w.z, h.w * w.w)));
                const float ex = __builtin_amdgcn_exp2f(v);
                const float rr = __builtin_amdgcn_rcpf(ex + 1.0f);
                val[j] = fmaf(-2.0f, rr, 1.0f);
            }
            __builtin_nontemporal_store(val, dst2 + i);
        }
    }
}

extern "C" void kernel_launch(void* const* d_in, const int* in_sizes, int n_in,
                              void* d_out, int out_size, void* d_ws, size_t ws_size,
                              hipStream_t stream) {
    const float* x   = (const float*)d_in[0];
    const float* q1w = (const float*)d_in[1];
    const float* q1b = (const float*)d_in[2];
    const float* k1w = (const float*)d_in[3];
    const float* k1b = (const float*)d_in[4];
    const float* v1w = (const float*)d_in[5];
    const float* v1b = (const float*)d_in[6];
    const float* q2w = (const float*)d_in[7];
    const float* q2b = (const float*)d_in[8];
    const float* k2w = (const float*)d_in[9];
    const float* k2b = (const float*)d_in[10];
    const float* v2w = (const float*)d_in[11];
    const float* v2b = (const float*)d_in[12];

    const long long B = 131072LL;
    float* out1 = (float*)d_out;
    float* out2 = out1 + B * SS * NV1;

    const int nblocks = (int)(B / NB);  // 16384
    fused_dual_attn<<<nblocks, THREADS, 0, stream>>>(
        x, q1w, q1b, k1w, k1b, v1w, v1b,
        q2w, q2b, k2w, k2b, v2w, v2b, out1, out2);
}

// Round 8
// 152.314 us; speedup vs baseline: 1.1048x; 1.1048x over previous
//
#include <hip/hip_runtime.h>

#define SS 30
#define QQ 16
#define NV1 21
#define NV2 11
#define NVT 32
#define NB 16                  // batches per block
#define ROWS (NB * SS)         // 480
#define CT (NB * (SS / 2))     // 240 compute threads (2 rows each)
#define THREADS 256

#define LOG2E 1.44269504088896340736f

typedef float v2f __attribute__((ext_vector_type(2)));
typedef float v4f __attribute__((ext_vector_type(4)));

__device__ __forceinline__ v2f bcast(float x) { v2f r; r.x = x; r.y = x; return r; }
__device__ __forceinline__ v2f pkfma(v2f a, v2f b, v2f c) {
    return __builtin_elementwise_fma(a, b, c);   // -> v_pk_fma_f32 on gfx950
}

__global__ __launch_bounds__(THREADS, 3) void fused_dual_attn(
    const float* __restrict__ x,
    const float* __restrict__ q1w, const float* __restrict__ q1b,
    const float* __restrict__ k1w, const float* __restrict__ k1b,
    const float* __restrict__ v1w, const float* __restrict__ v1b,
    const float* __restrict__ q2w, const float* __restrict__ q2b,
    const float* __restrict__ k2w, const float* __restrict__ k2b,
    const float* __restrict__ v2w, const float* __restrict__ v2b,
    float* __restrict__ out1, float* __restrict__ out2)
{
    __shared__ v4f xsv[ROWS];                    // 7.68 KB staged x
    __shared__ float cm[2][20];                  // per branch: log2e*(M[16], w[4])
    __shared__ v4f  vwt[NVT];                    // V weights * 2*log2e
    __shared__ float vbl[NVT];                   // V bias * 2*log2e
    __shared__ alignas(16) float stage[ROWS * NV1];  // 40.3 KB, reused for branch 2

    const int tid = threadIdx.x;
    const long long blk = blockIdx.x;

    // ---- per-block weight-derived constants (scaled by log2e) ----
    if (tid < 40) {
        const int br = tid / 20, idx = tid % 20;
        const float* qw = br ? q2w : q1w;
        const float* qb = br ? q2b : q1b;
        const float* kw = br ? k2w : k1w;
        float acc = 0.f;
        if (idx < 16) {
            const int d = idx >> 2, e = idx & 3;
            #pragma unroll
            for (int q = 0; q < QQ; ++q) acc += qw[d * QQ + q] * kw[e * QQ + q];
        } else {
            const int e = idx - 16;
            #pragma unroll
            for (int q = 0; q < QQ; ++q) acc += kw[e * QQ + q] * qb[q];
        }
        cm[br][idx] = acc * LOG2E;
    }
    if (tid >= 64 && tid < 64 + NVT) {
        const int o = tid - 64;
        const float s2l = 2.0f * LOG2E;
        v4f w;
        if (o < NV1) {
            w.x = v1w[o] * s2l; w.y = v1w[NV1 + o] * s2l;
            w.z = v1w[2 * NV1 + o] * s2l; w.w = v1w[3 * NV1 + o] * s2l;
            vbl[o] = v1b[o] * s2l;
        } else {
            const int p = o - NV1;
            w.x = v2w[p] * s2l; w.y = v2w[NV2 + p] * s2l;
            w.z = v2w[2 * NV2 + p] * s2l; w.w = v2w[3 * NV2 + p] * s2l;
            vbl[o] = v2b[p] * s2l;
        }
        vwt[o] = w;
    }

    // ---- stage x (coalesced, nontemporal) ----
    {
        const v4f* xg = reinterpret_cast<const v4f*>(x) + blk * ROWS;
        for (int i = tid; i < ROWS; i += THREADS)
            xsv[i] = __builtin_nontemporal_load(xg + i);
    }
    __syncthreads();

    // ---- main loop: 2 rows per thread (row-packed lo/hi), h stays in registers ----
    int lrowA = 0, lrowB = 0;
    v2f h1p[4], h2p[4];
    if (tid < CT) {
        const int batch = (unsigned)tid / 15;
        const int sA = tid - batch * 15;
        lrowA = batch * SS + sA;
        lrowB = lrowA + 15;
        const v4f* xb = xsv + batch * SS;
        const v4f xA = xsv[lrowA];
        const v4f xB = xsv[lrowB];

        v2f g1p[4], g2p[4];
        #pragma unroll
        for (int e = 0; e < 4; ++e) {
            g1p[e].x = cm[0][16 + e] + xA.x * cm[0][e] + xA.y * cm[0][4 + e]
                     + xA.z * cm[0][8 + e] + xA.w * cm[0][12 + e];
            g1p[e].y = cm[0][16 + e] + xB.x * cm[0][e] + xB.y * cm[0][4 + e]
                     + xB.z * cm[0][8 + e] + xB.w * cm[0][12 + e];
            g2p[e].x = cm[1][16 + e] + xA.x * cm[1][e] + xA.y * cm[1][4 + e]
                     + xA.z * cm[1][8 + e] + xA.w * cm[1][12 + e];
            g2p[e].y = cm[1][16 + e] + xB.x * cm[1][e] + xB.y * cm[1][4 + e]
                     + xB.z * cm[1][8 + e] + xB.w * cm[1][12 + e];
        }

        v2f sum1 = {0.f, 0.f}, sum2 = {0.f, 0.f};
        #pragma unroll
        for (int e = 0; e < 4; ++e) { h1p[e] = sum1; h2p[e] = sum1; }

        #pragma unroll
        for (int t = 0; t < SS; ++t) {
            const v4f xt = xb[t];
            const v2f bx = bcast(xt.x), by = bcast(xt.y), bz = bcast(xt.z), bw = bcast(xt.w);
            v2f s1 = g1p[3] * bw;
            s1 = pkfma(g1p[2], bz, s1);
            s1 = pkfma(g1p[1], by, s1);
            s1 = pkfma(g1p[0], bx, s1);
            v2f s2 = g2p[3] * bw;
            s2 = pkfma(g2p[2], bz, s2);
            s2 = pkfma(g2p[1], by, s2);
            s2 = pkfma(g2p[0], bx, s2);
            v2f p1, p2;
            p1.x = __builtin_amdgcn_exp2f(s1.x);
            p1.y = __builtin_amdgcn_exp2f(s1.y);
            p2.x = __builtin_amdgcn_exp2f(s2.x);
            p2.y = __builtin_amdgcn_exp2f(s2.y);
            sum1 = sum1 + p1;
            sum2 = sum2 + p2;
            h1p[0] = pkfma(p1, bx, h1p[0]);
            h1p[1] = pkfma(p1, by, h1p[1]);
            h1p[2] = pkfma(p1, bz, h1p[2]);
            h1p[3] = pkfma(p1, bw, h1p[3]);
            h2p[0] = pkfma(p2, bx, h2p[0]);
            h2p[1] = pkfma(p2, by, h2p[1]);
            h2p[2] = pkfma(p2, bz, h2p[2]);
            h2p[3] = pkfma(p2, bw, h2p[3]);
        }
        v2f inv1, inv2;
        inv1.x = __builtin_amdgcn_rcpf(sum1.x);
        inv1.y = __builtin_amdgcn_rcpf(sum1.y);
        inv2.x = __builtin_amdgcn_rcpf(sum2.x);
        inv2.y = __builtin_amdgcn_rcpf(sum2.y);
        #pragma unroll
        for (int e = 0; e < 4; ++e) { h1p[e] = h1p[e] * inv1; h2p[e] = h2p[e] * inv2; }
    }

    // ---- branch-1 epilogue: V-projection + tanh, packed over (rowA,rowB) ----
    if (tid < CT) {
        float* sA = stage + lrowA * NV1;
        float* sB = stage + lrowB * NV1;
        #pragma unroll
        for (int o = 0; o < NV1; ++o) {
            const v4f w = vwt[o];                 // uniform -> broadcast read
            v2f sp = bcast(vbl[o]);
            sp = pkfma(h1p[3], bcast(w.w), sp);
            sp = pkfma(h1p[2], bcast(w.z), sp);
            sp = pkfma(h1p[1], bcast(w.y), sp);
            sp = pkfma(h1p[0], bcast(w.x), sp);
            v2f ex;
            ex.x = __builtin_amdgcn_exp2f(sp.x);
            ex.y = __builtin_amdgcn_exp2f(sp.y);
            sA[o] = fmaf(-2.0f, __builtin_amdgcn_rcpf(ex.x + 1.0f), 1.0f);
            sB[o] = fmaf(-2.0f, __builtin_amdgcn_rcpf(ex.y + 1.0f), 1.0f);
        }
    }
    __syncthreads();
    {
        const int n1 = ROWS * NV1 / 4;   // 2520
        v4f* dst1 = reinterpret_cast<v4f*>(out1) + blk * n1;
        const v4f* src = reinterpret_cast<const v4f*>(stage);
        for (int i = tid; i < n1; i += THREADS)
            __builtin_nontemporal_store(src[i], dst1 + i);
    }
    __syncthreads();

    // ---- branch-2 epilogue (stage buffer reused) ----
    if (tid < CT) {
        float* sA = stage + lrowA * NV2;
        float* sB = stage + lrowB * NV2;
        #pragma unroll
        for (int o = 0; o < NV2; ++o) {
            const v4f w = vwt[NV1 + o];
            v2f sp = bcast(vbl[NV1 + o]);
            sp = pkfma(h2p[3], bcast(w.w), sp);
            sp = pkfma(h2p[2], bcast(w.z), sp);
            sp = pkfma(h2p[1], bcast(w.y), sp);
            sp = pkfma(h2p[0], bcast(w.x), sp);
            v2f ex;
            ex.x = __builtin_amdgcn_exp2f(sp.x);
            ex.y = __builtin_amdgcn_exp2f(sp.y);
            sA[o] = fmaf(-2.0f, __builtin_amdgcn_rcpf(ex.x + 1.0f), 1.0f);
            sB[o] = fmaf(-2.0f, __builtin_amdgcn_rcpf(ex.y + 1.0f), 1.0f);
        }
    }
    __syncthreads();
    {
        const int n2 = ROWS * NV2 / 4;   // 1320
        v4f* dst2 = reinterpret_cast<v4f*>(out2) + blk * n2;
        const v4f* src = reinterpret_cast<const v4f*>(stage);
        for (int i = tid; i < n2; i += THREADS)
            __builtin_nontemporal_store(src[i], dst2 + i);
    }
}

extern "C" void kernel_launch(void* const* d_in, const int* in_sizes, int n_in,
                              void* d_out, int out_size, void* d_ws, size_t ws_size,
                              hipStream_t stream) {
    const float* x   = (const float*)d_in[0];
    const float* q1w = (const float*)d_in[1];
    const float* q1b = (const float*)d_in[2];
    const float* k1w = (const float*)d_in[3];
    const float* k1b = (const float*)d_in[4];
    const float* v1w = (const float*)d_in[5];
    const float* v1b = (const float*)d_in[6];
    const float* q2w = (const float*)d_in[7];
    const float* q2b = (const float*)d_in[8];
    const float* k2w = (const float*)d_in[9];
    const float* k2b = (const float*)d_in[10];
    const float* v2w = (const float*)d_in[11];
    const float* v2b = (const float*)d_in[12];

    const long long B = 131072LL;
    float* out1 = (float*)d_out;
    float* out2 = out1 + B * SS * NV1;

    const int nblocks = (int)(B / NB);  // 8192
    fused_dual_attn<<<nblocks, THREADS, 0, stream>>>(
        x, q1w, q1b, k1w, k1b, v1w, v1b,
        q2w, q2b, k2w, k2b, v2w, v2b, out1, out2);
}

// Round 9
// 145.520 us; speedup vs baseline: 1.1564x; 1.0467x over previous
//
#include <hip/hip_runtime.h>

#define SS 30
#define QQ 16
#define NV1 21
#define NV2 11
#define NVT 32
#define NBPB 4                 // batches per block (single wave)
#define ROWS (NBPB * SS)       // 120
#define THREADS 64

#define LOG2E 1.44269504088896340736f

typedef float v2f __attribute__((ext_vector_type(2)));
typedef float v4f __attribute__((ext_vector_type(4)));

__device__ __forceinline__ v2f bcast(float x) { v2f r; r.x = x; r.y = x; return r; }
__device__ __forceinline__ v2f pkfma(v2f a, v2f b, v2f c) {
    return __builtin_elementwise_fma(a, b, c);   // -> v_pk_fma_f32 on gfx950
}

// ---- kernel 1: one block precomputes weight-derived constants into ws ----
// ws layout (floats): [0..39] cm (log2e*M,w for both branches)
//                     [40..167] vwt as 32 x v4f (V weights * 2*log2e)
//                     [168..199] vbl (V bias * 2*log2e)
__global__ __launch_bounds__(64) void precompute_consts(
    const float* __restrict__ q1w, const float* __restrict__ q1b,
    const float* __restrict__ k1w,
    const float* __restrict__ q2w, const float* __restrict__ q2b,
    const float* __restrict__ k2w,
    const float* __restrict__ v1w, const float* __restrict__ v1b,
    const float* __restrict__ v2w, const float* __restrict__ v2b,
    float* __restrict__ ws)
{
    const int tid = threadIdx.x;
    if (tid < 40) {
        const int br = tid / 20, idx = tid % 20;
        const float* qw = br ? q2w : q1w;
        const float* qb = br ? q2b : q1b;
        const float* kw = br ? k2w : k1w;
        float acc = 0.f;
        if (idx < 16) {
            const int d = idx >> 2, e = idx & 3;
            #pragma unroll
            for (int q = 0; q < QQ; ++q) acc += qw[d * QQ + q] * kw[e * QQ + q];
        } else {
            const int e = idx - 16;
            #pragma unroll
            for (int q = 0; q < QQ; ++q) acc += kw[e * QQ + q] * qb[q];
        }
        ws[tid] = acc * LOG2E;
    }
    if (tid < NVT) {
        const float s2l = 2.0f * LOG2E;
        v4f w; float b;
        if (tid < NV1) {
            w.x = v1w[tid] * s2l;          w.y = v1w[NV1 + tid] * s2l;
            w.z = v1w[2 * NV1 + tid] * s2l; w.w = v1w[3 * NV1 + tid] * s2l;
            b = v1b[tid] * s2l;
        } else {
            const int p = tid - NV1;
            w.x = v2w[p] * s2l;            w.y = v2w[NV2 + p] * s2l;
            w.z = v2w[2 * NV2 + p] * s2l;  w.w = v2w[3 * NV2 + p] * s2l;
            b = v2b[p] * s2l;
        }
        reinterpret_cast<v4f*>(ws + 40)[tid] = w;
        ws[168 + tid] = b;
    }
}

// ---- kernel 2: single-wave blocks, 4 batches each; fully skewed pipelines ----
__global__ __launch_bounds__(THREADS, 4) void fused_dual_attn(
    const float* __restrict__ x, const float* __restrict__ ws,
    float* __restrict__ out1, float* __restrict__ out2)
{
    __shared__ float cm[40];
    __shared__ v4f  vwt[NVT];
    __shared__ float vbl[NVT];
    __shared__ v4f  xsv[ROWS];                       // 1.92 KB
    __shared__ alignas(16) float stage[ROWS * NV1];  // 10.08 KB, reused for branch 2

    const int tid = threadIdx.x;
    const long long blk = blockIdx.x;

    // prologue: constants from ws (L2-cached) + stage x
    if (tid < 40) cm[tid] = ws[tid];
    if (tid < NVT) {
        vwt[tid] = reinterpret_cast<const v4f*>(ws + 40)[tid];
        vbl[tid] = ws[168 + tid];
    }
    {
        const v4f* xg = reinterpret_cast<const v4f*>(x) + blk * ROWS;
        xsv[tid] = __builtin_nontemporal_load(xg + tid);
        if (tid < ROWS - 64) xsv[64 + tid] = __builtin_nontemporal_load(xg + 64 + tid);
    }
    __syncthreads();

    // main loop: 2 rows per thread (row-packed lo/hi), h stays in registers
    int lrowA = 0, lrowB = 0;
    v2f h1p[4], h2p[4];
    if (tid < 60) {
        const int batch = (unsigned)tid / 15;
        const int sA = tid - batch * 15;
        lrowA = batch * SS + sA;
        lrowB = lrowA + 15;
        const v4f* xb = xsv + batch * SS;
        const v4f xA = xsv[lrowA];
        const v4f xB = xsv[lrowB];

        v2f g1p[4], g2p[4];
        #pragma unroll
        for (int e = 0; e < 4; ++e) {
            g1p[e].x = cm[16 + e] + xA.x * cm[e] + xA.y * cm[4 + e]
                     + xA.z * cm[8 + e] + xA.w * cm[12 + e];
            g1p[e].y = cm[16 + e] + xB.x * cm[e] + xB.y * cm[4 + e]
                     + xB.z * cm[8 + e] + xB.w * cm[12 + e];
            g2p[e].x = cm[36 + e] + xA.x * cm[20 + e] + xA.y * cm[24 + e]
                     + xA.z * cm[28 + e] + xA.w * cm[32 + e];
            g2p[e].y = cm[36 + e] + xB.x * cm[20 + e] + xB.y * cm[24 + e]
                     + xB.z * cm[28 + e] + xB.w * cm[32 + e];
        }

        v2f sum1 = {0.f, 0.f}, sum2 = {0.f, 0.f};
        #pragma unroll
        for (int e = 0; e < 4; ++e) { h1p[e] = sum1; h2p[e] = sum1; }

        #pragma unroll
        for (int t = 0; t < SS; ++t) {
            const v4f xt = xb[t];
            const v2f bx = bcast(xt.x), by = bcast(xt.y), bz = bcast(xt.z), bw = bcast(xt.w);
            v2f s1 = g1p[3] * bw;
            s1 = pkfma(g1p[2], bz, s1);
            s1 = pkfma(g1p[1], by, s1);
            s1 = pkfma(g1p[0], bx, s1);
            v2f s2 = g2p[3] * bw;
            s2 = pkfma(g2p[2], bz, s2);
            s2 = pkfma(g2p[1], by, s2);
            s2 = pkfma(g2p[0], bx, s2);
            v2f p1, p2;
            p1.x = __builtin_amdgcn_exp2f(s1.x);
            p1.y = __builtin_amdgcn_exp2f(s1.y);
            p2.x = __builtin_amdgcn_exp2f(s2.x);
            p2.y = __builtin_amdgcn_exp2f(s2.y);
            sum1 = sum1 + p1;
            sum2 = sum2 + p2;
            h1p[0] = pkfma(p1, bx, h1p[0]);
            h1p[1] = pkfma(p1, by, h1p[1]);
            h1p[2] = pkfma(p1, bz, h1p[2]);
            h1p[3] = pkfma(p1, bw, h1p[3]);
            h2p[0] = pkfma(p2, bx, h2p[0]);
            h2p[1] = pkfma(p2, by, h2p[1]);
            h2p[2] = pkfma(p2, bz, h2p[2]);
            h2p[3] = pkfma(p2, bw, h2p[3]);
        }
        v2f inv1, inv2;
        inv1.x = __builtin_amdgcn_rcpf(sum1.x);
        inv1.y = __builtin_amdgcn_rcpf(sum1.y);
        inv2.x = __builtin_amdgcn_rcpf(sum2.x);
        inv2.y = __builtin_amdgcn_rcpf(sum2.y);
        #pragma unroll
        for (int e = 0; e < 4; ++e) { h1p[e] = h1p[e] * inv1; h2p[e] = h2p[e] * inv2; }
    }

    // branch-1 epilogue: V-projection + tanh (w reads are wave-uniform broadcasts)
    if (tid < 60) {
        float* sA = stage + lrowA * NV1;
        float* sB = stage + lrowB * NV1;
        #pragma unroll
        for (int o = 0; o < NV1; ++o) {
            const v4f w = vwt[o];
            v2f sp = bcast(vbl[o]);
            sp = pkfma(h1p[3], bcast(w.w), sp);
            sp = pkfma(h1p[2], bcast(w.z), sp);
            sp = pkfma(h1p[1], bcast(w.y), sp);
            sp = pkfma(h1p[0], bcast(w.x), sp);
            v2f ex;
            ex.x = __builtin_amdgcn_exp2f(sp.x);
            ex.y = __builtin_amdgcn_exp2f(sp.y);
            sA[o] = fmaf(-2.0f, __builtin_amdgcn_rcpf(ex.x + 1.0f), 1.0f);
            sB[o] = fmaf(-2.0f, __builtin_amdgcn_rcpf(ex.y + 1.0f), 1.0f);
        }
    }
    __syncthreads();
    {
        const int n1 = ROWS * NV1 / 4;   // 630
        v4f* dst1 = reinterpret_cast<v4f*>(out1) + blk * n1;
        const v4f* src = reinterpret_cast<const v4f*>(stage);
        for (int i = tid; i < n1; i += THREADS)
            __builtin_nontemporal_store(src[i], dst1 + i);
    }
    __syncthreads();

    // branch-2 epilogue (stage buffer reused)
    if (tid < 60) {
        float* sA = stage + lrowA * NV2;
        float* sB = stage + lrowB * NV2;
        #pragma unroll
        for (int o = 0; o < NV2; ++o) {
            const v4f w = vwt[NV1 + o];
            v2f sp = bcast(vbl[NV1 + o]);
            sp = pkfma(h2p[3], bcast(w.w), sp);
            sp = pkfma(h2p[2], bcast(w.z), sp);
            sp = pkfma(h2p[1], bcast(w.y), sp);
            sp = pkfma(h2p[0], bcast(w.x), sp);
            v2f ex;
            ex.x = __builtin_amdgcn_exp2f(sp.x);
            ex.y = __builtin_amdgcn_exp2f(sp.y);
            sA[o] = fmaf(-2.0f, __builtin_amdgcn_rcpf(ex.x + 1.0f), 1.0f);
            sB[o] = fmaf(-2.0f, __builtin_amdgcn_rcpf(ex.y + 1.0f), 1.0f);
        }
    }
    __syncthreads();
    {
        const int n2 = ROWS * NV2 / 4;   // 330
        v4f* dst2 = reinterpret_cast<v4f*>(out2) + blk * n2;
        const v4f* src = reinterpret_cast<const v4f*>(stage);
        for (int i = tid; i < n2; i += THREADS)
            __builtin_nontemporal_store(src[i], dst2 + i);
    }
}

extern "C" void kernel_launch(void* const* d_in, const int* in_sizes, int n_in,
                              void* d_out, int out_size, void* d_ws, size_t ws_size,
                              hipStream_t stream) {
    const float* x   = (const float*)d_in[0];
    const float* q1w = (const float*)d_in[1];
    const float* q1b = (const float*)d_in[2];
    const float* k1w = (const float*)d_in[3];
    const float* v1w = (const float*)d_in[5];
    const float* v1b = (const float*)d_in[6];
    const float* q2w = (const float*)d_in[7];
    const float* q2b = (const float*)d_in[8];
    const float* k2w = (const float*)d_in[9];
    const float* v2w = (const float*)d_in[11];
    const float* v2b = (const float*)d_in[12];

    const long long B = 131072LL;
    float* out1 = (float*)d_out;
    float* out2 = out1 + B * SS * NV1;
    float* ws   = (float*)d_ws;

    precompute_consts<<<1, 64, 0, stream>>>(q1w, q1b, k1w, q2w, q2b, k2w,
                                            v1w, v1b, v2w, v2b, ws);

    const int nblocks = (int)(B / NBPB);  // 32768
    fused_dual_attn<<<nblocks, THREADS, 0, stream>>>(x, ws, out1, out2);
}

// Round 10
// 145.005 us; speedup vs baseline: 1.1605x; 1.0035x over previous
//
#include <hip/hip_runtime.h>

#define SS 30
#define QQ 16
#define NV1 21
#define NV2 11
#define NVT 32
#define NBPB 2                 // batches per block (single wave, 1 row/thread)
#define ROWS (NBPB * SS)       // 60
#define THREADS 64

#define LOG2E 1.44269504088896340736f

typedef float v2f __attribute__((ext_vector_type(2)));
typedef float v4f __attribute__((ext_vector_type(4)));

__device__ __forceinline__ v2f bcast(float x) { v2f r; r.x = x; r.y = x; return r; }
__device__ __forceinline__ v2f pkfma(v2f a, v2f b, v2f c) {
    return __builtin_elementwise_fma(a, b, c);   // -> v_pk_fma_f32 on gfx950
}

// ---- kernel 1: one block precomputes weight-derived constants into ws ----
// ws layout (floats): [0..39] cm (log2e*M,w for both branches)
//                     [40..167] vwt as 32 x v4f (V weights * 2*log2e)
//                     [168..199] vbl (V bias * 2*log2e)
__global__ __launch_bounds__(64) void precompute_consts(
    const float* __restrict__ q1w, const float* __restrict__ q1b,
    const float* __restrict__ k1w,
    const float* __restrict__ q2w, const float* __restrict__ q2b,
    const float* __restrict__ k2w,
    const float* __restrict__ v1w, const float* __restrict__ v1b,
    const float* __restrict__ v2w, const float* __restrict__ v2b,
    float* __restrict__ ws)
{
    const int tid = threadIdx.x;
    if (tid < 40) {
        const int br = tid / 20, idx = tid % 20;
        const float* qw = br ? q2w : q1w;
        const float* qb = br ? q2b : q1b;
        const float* kw = br ? k2w : k1w;
        float acc = 0.f;
        if (idx < 16) {
            const int d = idx >> 2, e = idx & 3;
            #pragma unroll
            for (int q = 0; q < QQ; ++q) acc += qw[d * QQ + q] * kw[e * QQ + q];
        } else {
            const int e = idx - 16;
            #pragma unroll
            for (int q = 0; q < QQ; ++q) acc += kw[e * QQ + q] * qb[q];
        }
        ws[tid] = acc * LOG2E;
    }
    if (tid < NVT) {
        const float s2l = 2.0f * LOG2E;
        v4f w; float b;
        if (tid < NV1) {
            w.x = v1w[tid] * s2l;          w.y = v1w[NV1 + tid] * s2l;
            w.z = v1w[2 * NV1 + tid] * s2l; w.w = v1w[3 * NV1 + tid] * s2l;
            b = v1b[tid] * s2l;
        } else {
            const int p = tid - NV1;
            w.x = v2w[p] * s2l;            w.y = v2w[NV2 + p] * s2l;
            w.z = v2w[2 * NV2 + p] * s2l;  w.w = v2w[3 * NV2 + p] * s2l;
            b = v2b[p] * s2l;
        }
        reinterpret_cast<v4f*>(ws + 40)[tid] = w;
        ws[168 + tid] = b;
    }
}

// ---- kernel 2: single-wave blocks, 2 batches, 1 row/thread, branch-packed ----
__global__ __launch_bounds__(THREADS, 8) void fused_dual_attn(
    const float* __restrict__ x, const float* __restrict__ ws,
    float* __restrict__ out1, float* __restrict__ out2)
{
    __shared__ float cm[40];
    __shared__ v4f  vwt[NVT];
    __shared__ float vbl[NVT];
    __shared__ v4f  xsv[ROWS];                       // 0.96 KB
    __shared__ alignas(16) float stage[ROWS * NV1];  // 5.04 KB, reused for branch 2

    const int tid = threadIdx.x;
    const long long blk = blockIdx.x;

    // prologue: constants from ws (L2-cached) + stage x
    if (tid < 40) cm[tid] = ws[tid];
    if (tid < NVT) {
        vwt[tid] = reinterpret_cast<const v4f*>(ws + 40)[tid];
        vbl[tid] = ws[168 + tid];
    }
    if (tid < ROWS) {
        const v4f* xg = reinterpret_cast<const v4f*>(x) + blk * ROWS;
        xsv[tid] = __builtin_nontemporal_load(xg + tid);
    }
    __syncthreads();

    // main loop: one row per thread; v2f lanes pack (branch1, branch2)
    v2f hp[4] = {{0.f,0.f},{0.f,0.f},{0.f,0.f},{0.f,0.f}};
    if (tid < ROWS) {
        const int batch = (tid >= SS) ? 1 : 0;
        const v4f* xb = xsv + batch * SS;
        const v4f xr = xsv[tid];

        v2f g[4];
        #pragma unroll
        for (int e = 0; e < 4; ++e) {
            g[e].x = cm[16 + e] + xr.x * cm[e] + xr.y * cm[4 + e]
                   + xr.z * cm[8 + e] + xr.w * cm[12 + e];
            g[e].y = cm[36 + e] + xr.x * cm[20 + e] + xr.y * cm[24 + e]
                   + xr.z * cm[28 + e] + xr.w * cm[32 + e];
        }

        v2f sum = {0.f, 0.f};
        #pragma unroll
        for (int t = 0; t < SS; ++t) {
            const v4f xt = xb[t];
            const v2f bx = bcast(xt.x), by = bcast(xt.y), bz = bcast(xt.z), bw = bcast(xt.w);
            v2f s = g[3] * bw;
            s = pkfma(g[2], bz, s);
            s = pkfma(g[1], by, s);
            s = pkfma(g[0], bx, s);
            v2f p;
            p.x = __builtin_amdgcn_exp2f(s.x);
            p.y = __builtin_amdgcn_exp2f(s.y);
            sum = sum + p;
            hp[0] = pkfma(p, bx, hp[0]);
            hp[1] = pkfma(p, by, hp[1]);
            hp[2] = pkfma(p, bz, hp[2]);
            hp[3] = pkfma(p, bw, hp[3]);
        }
        v2f inv;
        inv.x = __builtin_amdgcn_rcpf(sum.x);
        inv.y = __builtin_amdgcn_rcpf(sum.y);
        #pragma unroll
        for (int e = 0; e < 4; ++e) hp[e] = hp[e] * inv;
    }

    // branch-1 epilogue: V-projection + tanh (w reads are wave-uniform broadcasts)
    if (tid < ROWS) {
        float* sp = stage + tid * NV1;
        #pragma unroll
        for (int o = 0; o < NV1; ++o) {
            const v4f w = vwt[o];
            float v = vbl[o];
            v = fmaf(hp[0].x, w.x, v);
            v = fmaf(hp[1].x, w.y, v);
            v = fmaf(hp[2].x, w.z, v);
            v = fmaf(hp[3].x, w.w, v);
            const float ex = __builtin_amdgcn_exp2f(v);   // exp(2*orig), scale folded
            sp[o] = fmaf(-2.0f, __builtin_amdgcn_rcpf(ex + 1.0f), 1.0f);
        }
    }
    __syncthreads();
    {
        const int n1 = ROWS * NV1 / 4;   // 315
        v4f* dst1 = reinterpret_cast<v4f*>(out1) + blk * n1;
        const v4f* src = reinterpret_cast<const v4f*>(stage);
        for (int i = tid; i < n1; i += THREADS)
            __builtin_nontemporal_store(src[i], dst1 + i);
    }
    __syncthreads();

    // branch-2 epilogue (stage buffer reused)
    if (tid < ROWS) {
        float* sp = stage + tid * NV2;
        #pragma unroll
        for (int o = 0; o < NV2; ++o) {
            const v4f w = vwt[NV1 + o];
            float v = vbl[NV1 + o];
            v = fmaf(hp[0].y, w.x, v);
            v = fmaf(hp[1].y, w.y, v);
            v = fmaf(hp[2].y, w.z, v);
            v = fmaf(hp[3].y, w.w, v);
            const float ex = __builtin_amdgcn_exp2f(v);
            sp[o] = fmaf(-2.0f, __builtin_amdgcn_rcpf(ex + 1.0f), 1.0f);
        }
    }
    __syncthreads();
    {
        const int n2 = ROWS * NV2 / 4;   // 165
        v4f* dst2 = reinterpret_cast<v4f*>(out2) + blk * n2;
        const v4f* src = reinterpret_cast<const v4f*>(stage);
        for (int i = tid; i < n2; i += THREADS)
            __builtin_nontemporal_store(src[i], dst2 + i);
    }
}

extern "C" void kernel_launch(void* const* d_in, const int* in_sizes, int n_in,
                              void* d_out, int out_size, void* d_ws, size_t ws_size,
                              hipStream_t stream) {
    const float* x   = (const float*)d_in[0];
    const float* q1w = (const float*)d_in[1];
    const float* q1b = (const float*)d_in[2];
    const float* k1w = (const float*)d_in[3];
    const float* v1w = (const float*)d_in[5];
    const float* v1b = (const float*)d_in[6];
    const float* q2w = (const float*)d_in[7];
    const float* q2b = (const float*)d_in[8];
    const float* k2w = (const float*)d_in[9];
    const float* v2w = (const float*)d_in[11];
    const float* v2b = (const float*)d_in[12];

    const long long B = 131072LL;
    float* out1 = (float*)d_out;
    float* out2 = out1 + B * SS * NV1;
    float* ws   = (float*)d_ws;

    precompute_consts<<<1, 64, 0, stream>>>(q1w, q1b, k1w, q2w, q2b, k2w,
                                            v1w, v1b, v2w, v2b, ws);

    const int nblocks = (int)(B / NBPB);  // 65536
    fused_dual_attn<<<nblocks, THREADS, 0, stream>>>(x, ws, out1, out2);
}

// Round 11
// 135.427 us; speedup vs baseline: 1.2426x; 1.0707x over previous
//
#include <hip/hip_runtime.h>

#define SS 30
#define QQ 16
#define NV1 21
#define NV2 11
#define NVT 32
#define NBPB 2                 // batches per block (single wave, 1 row/thread)
#define ROWS (NBPB * SS)       // 60
#define THREADS 64

#define LOG2E 1.44269504088896340736f

typedef float v2f __attribute__((ext_vector_type(2)));
typedef float v4f __attribute__((ext_vector_type(4)));

__device__ __forceinline__ v2f bcast(float x) { v2f r; r.x = x; r.y = x; return r; }
__device__ __forceinline__ v2f pkfma(v2f a, v2f b, v2f c) {
    return __builtin_elementwise_fma(a, b, c);   // -> v_pk_fma_f32 on gfx950
}

// ---- kernel 1: one block precomputes weight-derived constants into ws ----
// ws layout (floats): [0..39] cm (log2e*M,w for both branches)
//                     [40..167] vwt as 32 x v4f (V weights * 2*log2e)
//                     [168..199] vbl (V bias * 2*log2e)
__global__ __launch_bounds__(64) void precompute_consts(
    const float* __restrict__ q1w, const float* __restrict__ q1b,
    const float* __restrict__ k1w,
    const float* __restrict__ q2w, const float* __restrict__ q2b,
    const float* __restrict__ k2w,
    const float* __restrict__ v1w, const float* __restrict__ v1b,
    const float* __restrict__ v2w, const float* __restrict__ v2b,
    float* __restrict__ ws)
{
    const int tid = threadIdx.x;
    if (tid < 40) {
        const int br = tid / 20, idx = tid % 20;
        const float* qw = br ? q2w : q1w;
        const float* qb = br ? q2b : q1b;
        const float* kw = br ? k2w : k1w;
        float acc = 0.f;
        if (idx < 16) {
            const int d = idx >> 2, e = idx & 3;
            #pragma unroll
            for (int q = 0; q < QQ; ++q) acc += qw[d * QQ + q] * kw[e * QQ + q];
        } else {
            const int e = idx - 16;
            #pragma unroll
            for (int q = 0; q < QQ; ++q) acc += kw[e * QQ + q] * qb[q];
        }
        ws[tid] = acc * LOG2E;
    }
    if (tid < NVT) {
        const float s2l = 2.0f * LOG2E;
        v4f w; float b;
        if (tid < NV1) {
            w.x = v1w[tid] * s2l;          w.y = v1w[NV1 + tid] * s2l;
            w.z = v1w[2 * NV1 + tid] * s2l; w.w = v1w[3 * NV1 + tid] * s2l;
            b = v1b[tid] * s2l;
        } else {
            const int p = tid - NV1;
            w.x = v2w[p] * s2l;            w.y = v2w[NV2 + p] * s2l;
            w.z = v2w[2 * NV2 + p] * s2l;  w.w = v2w[3 * NV2 + p] * s2l;
            b = v2b[p] * s2l;
        }
        reinterpret_cast<v4f*>(ws + 40)[tid] = w;
        ws[168 + tid] = b;
    }
}

// ---- kernel 2: single-wave blocks; x via L1, weights via scalar cache ----
__global__ __launch_bounds__(THREADS, 8) void fused_dual_attn(
    const float* __restrict__ x, const float* __restrict__ ws,
    float* __restrict__ out1, float* __restrict__ out2)
{
    __shared__ alignas(16) float stage[ROWS * NV1];  // 5.04 KB, only LDS user

    const int tid = threadIdx.x;
    const long long blk = blockIdx.x;
    const v4f* xgv = reinterpret_cast<const v4f*>(x) + blk * ROWS;

    // main loop: one row per thread; v2f lanes pack (branch1, branch2)
    v2f hp[4] = {{0.f,0.f},{0.f,0.f},{0.f,0.f},{0.f,0.f}};
    if (tid < ROWS) {
        const int batch = (tid >= SS) ? 1 : 0;
        const int boff = batch * SS;
        const v4f xr = xgv[tid];

        // g vectors from scalar-cached cm constants (compile-time ws indices)
        v2f g[4];
        #pragma unroll
        for (int e = 0; e < 4; ++e) {
            g[e].x = ws[16 + e] + xr.x * ws[e] + xr.y * ws[4 + e]
                   + xr.z * ws[8 + e] + xr.w * ws[12 + e];
            g[e].y = ws[36 + e] + xr.x * ws[20 + e] + xr.y * ws[24 + e]
                   + xr.z * ws[28 + e] + xr.w * ws[32 + e];
        }

        v2f sum = {0.f, 0.f};
        #pragma unroll
        for (int t = 0; t < SS; ++t) {
            const v4f xt = xgv[boff + t];      // L1-resident, <=2 lines/wave
            const v2f bx = bcast(xt.x), by = bcast(xt.y), bz = bcast(xt.z), bw = bcast(xt.w);
            v2f s = g[3] * bw;
            s = pkfma(g[2], bz, s);
            s = pkfma(g[1], by, s);
            s = pkfma(g[0], bx, s);
            v2f p;
            p.x = __builtin_amdgcn_exp2f(s.x);
            p.y = __builtin_amdgcn_exp2f(s.y);
            sum = sum + p;
            hp[0] = pkfma(p, bx, hp[0]);
            hp[1] = pkfma(p, by, hp[1]);
            hp[2] = pkfma(p, bz, hp[2]);
            hp[3] = pkfma(p, bw, hp[3]);
        }
        v2f inv;
        inv.x = __builtin_amdgcn_rcpf(sum.x);
        inv.y = __builtin_amdgcn_rcpf(sum.y);
        #pragma unroll
        for (int e = 0; e < 4; ++e) hp[e] = hp[e] * inv;
    }

    // branch-1 epilogue: V-projection + tanh; weights via s_load (no LDS)
    if (tid < ROWS) {
        float* sp = stage + tid * NV1;
        #pragma unroll
        for (int o = 0; o < NV1; ++o) {
            float v = ws[168 + o];
            v = fmaf(hp[0].x, ws[40 + 4 * o + 0], v);
            v = fmaf(hp[1].x, ws[40 + 4 * o + 1], v);
            v = fmaf(hp[2].x, ws[40 + 4 * o + 2], v);
            v = fmaf(hp[3].x, ws[40 + 4 * o + 3], v);
            const float ex = __builtin_amdgcn_exp2f(v);   // exp(2*orig), scale folded
            sp[o] = fmaf(-2.0f, __builtin_amdgcn_rcpf(ex + 1.0f), 1.0f);
        }
    }
    __syncthreads();
    {
        const int n1 = ROWS * NV1 / 4;   // 315
        v4f* dst1 = reinterpret_cast<v4f*>(out1) + blk * n1;
        const v4f* src = reinterpret_cast<const v4f*>(stage);
        for (int i = tid; i < n1; i += THREADS)
            __builtin_nontemporal_store(src[i], dst1 + i);
    }
    __syncthreads();

    // branch-2 epilogue (stage buffer reused)
    if (tid < ROWS) {
        float* sp = stage + tid * NV2;
        #pragma unroll
        for (int o = 0; o < NV2; ++o) {
            const int oo = NV1 + o;
            float v = ws[168 + oo];
            v = fmaf(hp[0].y, ws[40 + 4 * oo + 0], v);
            v = fmaf(hp[1].y, ws[40 + 4 * oo + 1], v);
            v = fmaf(hp[2].y, ws[40 + 4 * oo + 2], v);
            v = fmaf(hp[3].y, ws[40 + 4 * oo + 3], v);
            const float ex = __builtin_amdgcn_exp2f(v);
            sp[o] = fmaf(-2.0f, __builtin_amdgcn_rcpf(ex + 1.0f), 1.0f);
        }
    }
    __syncthreads();
    {
        const int n2 = ROWS * NV2 / 4;   // 165
        v4f* dst2 = reinterpret_cast<v4f*>(out2) + blk * n2;
        const v4f* src = reinterpret_cast<const v4f*>(stage);
        for (int i = tid; i < n2; i += THREADS)
            __builtin_nontemporal_store(src[i], dst2 + i);
    }
}

extern "C" void kernel_launch(void* const* d_in, const int* in_sizes, int n_in,
                              void* d_out, int out_size, void* d_ws, size_t ws_size,
                              hipStream_t stream) {
    const float* x   = (const float*)d_in[0];
    const float* q1w = (const float*)d_in[1];
    const float* q1b = (const float*)d_in[2];
    const float* k1w = (const float*)d_in[3];
    const float* v1w = (const float*)d_in[5];
    const float* v1b = (const float*)d_in[6];
    const float* q2w = (const float*)d_in[7];
    const float* q2b = (const float*)d_in[8];
    const float* k2w = (const float*)d_in[9];
    const float* v2w = (const float*)d_in[11];
    const float* v2b = (const float*)d_in[12];

    const long long B = 131072LL;
    float* out1 = (float*)d_out;
    float* out2 = out1 + B * SS * NV1;
    float* ws   = (float*)d_ws;

    precompute_consts<<<1, 64, 0, stream>>>(q1w, q1b, k1w, q2w, q2b, k2w,
                                            v1w, v1b, v2w, v2b, ws);

    const int nblocks = (int)(B / NBPB);  // 65536
    fused_dual_attn<<<nblocks, THREADS, 0, stream>>>(x, ws, out1, out2);
}

// Round 12
// 128.226 us; speedup vs baseline: 1.3124x; 1.0562x over previous
//
#include <hip/hip_runtime.h>

#define SS 30
#define QQ 16
#define NV1 21
#define NV2 11
#define NVT 32
#define NBPB 4                 // batches per block (single wave, 2 rows/thread)
#define ROWS (NBPB * SS)       // 120
#define THREADS 64

#define LOG2E 1.44269504088896340736f

typedef float v2f __attribute__((ext_vector_type(2)));
typedef float v4f __attribute__((ext_vector_type(4)));

__device__ __forceinline__ v2f bcast(float x) { v2f r; r.x = x; r.y = x; return r; }
__device__ __forceinline__ v2f pkfma(v2f a, v2f b, v2f c) {
    return __builtin_elementwise_fma(a, b, c);   // -> v_pk_fma_f32 on gfx950
}

// ---- kernel 1: one block precomputes weight-derived constants into ws ----
// ws layout (floats): [0..39] cm (log2e*M,w for both branches)
//                     [40..167] vwt as 32 x v4f (V weights * 2*log2e)
//                     [168..199] vbl (V bias * 2*log2e)
__global__ __launch_bounds__(64) void precompute_consts(
    const float* __restrict__ q1w, const float* __restrict__ q1b,
    const float* __restrict__ k1w,
    const float* __restrict__ q2w, const float* __restrict__ q2b,
    const float* __restrict__ k2w,
    const float* __restrict__ v1w, const float* __restrict__ v1b,
    const float* __restrict__ v2w, const float* __restrict__ v2b,
    float* __restrict__ ws)
{
    const int tid = threadIdx.x;
    if (tid < 40) {
        const int br = tid / 20, idx = tid % 20;
        const float* qw = br ? q2w : q1w;
        const float* qb = br ? q2b : q1b;
        const float* kw = br ? k2w : k1w;
        float acc = 0.f;
        if (idx < 16) {
            const int d = idx >> 2, e = idx & 3;
            #pragma unroll
            for (int q = 0; q < QQ; ++q) acc += qw[d * QQ + q] * kw[e * QQ + q];
        } else {
            const int e = idx - 16;
            #pragma unroll
            for (int q = 0; q < QQ; ++q) acc += kw[e * QQ + q] * qb[q];
        }
        ws[tid] = acc * LOG2E;
    }
    if (tid < NVT) {
        const float s2l = 2.0f * LOG2E;
        v4f w; float b;
        if (tid < NV1) {
            w.x = v1w[tid] * s2l;          w.y = v1w[NV1 + tid] * s2l;
            w.z = v1w[2 * NV1 + tid] * s2l; w.w = v1w[3 * NV1 + tid] * s2l;
            b = v1b[tid] * s2l;
        } else {
            const int p = tid - NV1;
            w.x = v2w[p] * s2l;            w.y = v2w[NV2 + p] * s2l;
            w.z = v2w[2 * NV2 + p] * s2l;  w.w = v2w[3 * NV2 + p] * s2l;
            b = v2b[p] * s2l;
        }
        reinterpret_cast<v4f*>(ws + 40)[tid] = w;
        ws[168 + tid] = b;
    }
}

// ---- kernel 2: single-wave blocks, 4 batches, 2 rows/thread (same batch) ----
__global__ __launch_bounds__(THREADS, 4) void fused_dual_attn(
    const float* __restrict__ x, const float* __restrict__ ws,
    float* __restrict__ out1, float* __restrict__ out2)
{
    __shared__ alignas(16) float stage[ROWS * NV1];  // 10.08 KB, only LDS user

    const int tid = threadIdx.x;
    const long long blk = blockIdx.x;
    const v4f* xgv = reinterpret_cast<const v4f*>(x) + blk * ROWS;

    // per-thread state: rows rA = batch*30 + s, rB = rA + 15 (same batch)
    // v2f lanes pack (branch1, branch2) for each row
    v2f hA[4] = {{0.f,0.f},{0.f,0.f},{0.f,0.f},{0.f,0.f}};
    v2f hB[4] = {{0.f,0.f},{0.f,0.f},{0.f,0.f},{0.f,0.f}};
    int rowA = 0, rowB = 0;

    if (tid < 60) {
        const int batch = (unsigned)tid / 15;
        const int sA = tid - batch * 15;
        rowA = batch * SS + sA;
        rowB = rowA + 15;
        const int boff = batch * SS;
        const v4f xra = xgv[rowA];
        const v4f xrb = xgv[rowB];

        // g vectors from scalar-cached constants (compile-time ws indices)
        v2f gA[4], gB[4];
        #pragma unroll
        for (int e = 0; e < 4; ++e) {
            gA[e].x = ws[16 + e] + xra.x * ws[e] + xra.y * ws[4 + e]
                    + xra.z * ws[8 + e] + xra.w * ws[12 + e];
            gA[e].y = ws[36 + e] + xra.x * ws[20 + e] + xra.y * ws[24 + e]
                    + xra.z * ws[28 + e] + xra.w * ws[32 + e];
            gB[e].x = ws[16 + e] + xrb.x * ws[e] + xrb.y * ws[4 + e]
                    + xrb.z * ws[8 + e] + xrb.w * ws[12 + e];
            gB[e].y = ws[36 + e] + xrb.x * ws[20 + e] + xrb.y * ws[24 + e]
                    + xrb.z * ws[28 + e] + xrb.w * ws[32 + e];
        }

        v2f sumA = {0.f, 0.f}, sumB = {0.f, 0.f};
        #pragma unroll
        for (int t = 0; t < SS; ++t) {
            const v4f xt = xgv[boff + t];      // L1-resident, 4-addr broadcast
            const v2f bx = bcast(xt.x), by = bcast(xt.y), bz = bcast(xt.z), bw = bcast(xt.w);
            v2f sA2 = gA[3] * bw;
            sA2 = pkfma(gA[2], bz, sA2);
            sA2 = pkfma(gA[1], by, sA2);
            sA2 = pkfma(gA[0], bx, sA2);
            v2f sB2 = gB[3] * bw;
            sB2 = pkfma(gB[2], bz, sB2);
            sB2 = pkfma(gB[1], by, sB2);
            sB2 = pkfma(gB[0], bx, sB2);
            v2f pA, pB;
            pA.x = __builtin_amdgcn_exp2f(sA2.x);
            pA.y = __builtin_amdgcn_exp2f(sA2.y);
            pB.x = __builtin_amdgcn_exp2f(sB2.x);
            pB.y = __builtin_amdgcn_exp2f(sB2.y);
            sumA = sumA + pA;
            sumB = sumB + pB;
            hA[0] = pkfma(pA, bx, hA[0]);
            hA[1] = pkfma(pA, by, hA[1]);
            hA[2] = pkfma(pA, bz, hA[2]);
            hA[3] = pkfma(pA, bw, hA[3]);
            hB[0] = pkfma(pB, bx, hB[0]);
            hB[1] = pkfma(pB, by, hB[1]);
            hB[2] = pkfma(pB, bz, hB[2]);
            hB[3] = pkfma(pB, bw, hB[3]);
        }
        v2f invA, invB;
        invA.x = __builtin_amdgcn_rcpf(sumA.x);
        invA.y = __builtin_amdgcn_rcpf(sumA.y);
        invB.x = __builtin_amdgcn_rcpf(sumB.x);
        invB.y = __builtin_amdgcn_rcpf(sumB.y);
        #pragma unroll
        for (int e = 0; e < 4; ++e) { hA[e] = hA[e] * invA; hB[e] = hB[e] * invB; }
    }

    // branch-1 epilogue: scalar V-projection + tanh (weights stay in SGPRs)
    if (tid < 60) {
        float* spA = stage + rowA * NV1;
        float* spB = stage + rowB * NV1;
        #pragma unroll
        for (int o = 0; o < NV1; ++o) {
            float vA = ws[168 + o];
            vA = fmaf(hA[0].x, ws[40 + 4 * o + 0], vA);
            vA = fmaf(hA[1].x, ws[40 + 4 * o + 1], vA);
            vA = fmaf(hA[2].x, ws[40 + 4 * o + 2], vA);
            vA = fmaf(hA[3].x, ws[40 + 4 * o + 3], vA);
            const float exA = __builtin_amdgcn_exp2f(vA);
            spA[o] = fmaf(-2.0f, __builtin_amdgcn_rcpf(exA + 1.0f), 1.0f);
            float vB = ws[168 + o];
            vB = fmaf(hB[0].x, ws[40 + 4 * o + 0], vB);
            vB = fmaf(hB[1].x, ws[40 + 4 * o + 1], vB);
            vB = fmaf(hB[2].x, ws[40 + 4 * o + 2], vB);
            vB = fmaf(hB[3].x, ws[40 + 4 * o + 3], vB);
            const float exB = __builtin_amdgcn_exp2f(vB);
            spB[o] = fmaf(-2.0f, __builtin_amdgcn_rcpf(exB + 1.0f), 1.0f);
        }
    }
    __syncthreads();
    {
        const int n1 = ROWS * NV1 / 4;   // 630
        v4f* dst1 = reinterpret_cast<v4f*>(out1) + blk * n1;
        const v4f* src = reinterpret_cast<const v4f*>(stage);
        #pragma unroll
        for (int k = 0; k < n1 / THREADS; ++k)
            __builtin_nontemporal_store(src[k * THREADS + tid], dst1 + k * THREADS + tid);
        {   // remainder 630 - 9*64 = 54
            const int i = (n1 / THREADS) * THREADS + tid;
            if (i < n1) __builtin_nontemporal_store(src[i], dst1 + i);
        }
    }
    __syncthreads();

    // branch-2 epilogue (stage buffer reused)
    if (tid < 60) {
        float* spA = stage + rowA * NV2;
        float* spB = stage + rowB * NV2;
        #pragma unroll
        for (int o = 0; o < NV2; ++o) {
            const int oo = NV1 + o;
            float vA = ws[168 + oo];
            vA = fmaf(hA[0].y, ws[40 + 4 * oo + 0], vA);
            vA = fmaf(hA[1].y, ws[40 + 4 * oo + 1], vA);
            vA = fmaf(hA[2].y, ws[40 + 4 * oo + 2], vA);
            vA = fmaf(hA[3].y, ws[40 + 4 * oo + 3], vA);
            const float exA = __builtin_amdgcn_exp2f(vA);
            spA[o] = fmaf(-2.0f, __builtin_amdgcn_rcpf(exA + 1.0f), 1.0f);
            float vB = ws[168 + oo];
            vB = fmaf(hB[0].y, ws[40 + 4 * oo + 0], vB);
            vB = fmaf(hB[1].y, ws[40 + 4 * oo + 1], vB);
            vB = fmaf(hB[2].y, ws[40 + 4 * oo + 2], vB);
            vB = fmaf(hB[3].y, ws[40 + 4 * oo + 3], vB);
            const float exB = __builtin_amdgcn_exp2f(vB);
            spB[o] = fmaf(-2.0f, __builtin_amdgcn_rcpf(exB + 1.0f), 1.0f);
        }
    }
    __syncthreads();
    {
        const int n2 = ROWS * NV2 / 4;   // 330
        v4f* dst2 = reinterpret_cast<v4f*>(out2) + blk * n2;
        const v4f* src = reinterpret_cast<const v4f*>(stage);
        #pragma unroll
        for (int k = 0; k < n2 / THREADS; ++k)
            __builtin_nontemporal_store(src[k * THREADS + tid], dst2 + k * THREADS + tid);
        {   // remainder 330 - 5*64 = 10
            const int i = (n2 / THREADS) * THREADS + tid;
            if (i < n2) __builtin_nontemporal_store(src[i], dst2 + i);
        }
    }
}

extern "C" void kernel_launch(void* const* d_in, const int* in_sizes, int n_in,
                              void* d_out, int out_size, void* d_ws, size_t ws_size,
                              hipStream_t stream) {
    const float* x   = (const float*)d_in[0];
    const float* q1w = (const float*)d_in[1];
    const float* q1b = (const float*)d_in[2];
    const float* k1w = (const float*)d_in[3];
    const float* v1w = (const float*)d_in[5];
    const float* v1b = (const float*)d_in[6];
    const float* q2w = (const float*)d_in[7];
    const float* q2b = (const float*)d_in[8];
    const float* k2w = (const float*)d_in[9];
    const float* v2w = (const float*)d_in[11];
    const float* v2b = (const float*)d_in[12];

    const long long B = 131072LL;
    float* out1 = (float*)d_out;
    float* out2 = out1 + B * SS * NV1;
    float* ws   = (float*)d_ws;

    precompute_consts<<<1, 64, 0, stream>>>(q1w, q1b, k1w, q2w, q2b, k2w,
                                            v1w, v1b, v2w, v2b, ws);

    const int nblocks = (int)(B / NBPB);  // 32768
    fused_dual_attn<<<nblocks, THREADS, 0, stream>>>(x, ws, out1, out2);
}